// Round 6
// baseline (2601.785 us; speedup 1.0000x reference)
//
#include <hip/hip_runtime.h>
#include <math.h>

#define NN 50000
#define NE 800000
#define DD 64
#define N_GCN 30
#define N_GGC 8
#define NB ((NN + 255) / 256)
#define NPB 6   // nodes per block-iteration in gru_fused

__device__ __forceinline__ float lane_bcast(float v, int k) {
    return __int_as_float(__builtin_amdgcn_readlane(__float_as_int(v), k));
}

// Force a value into a VGPR and pin it there (prevents the allocator from
// sinking the defining load into downstream loops — the recurring VGPR=40
// pathology of R2/R4/R5).
#define KEEP_VGPR(x) asm volatile("" : "+v"(x))

// ---------------- graph prep ----------------

__global__ void hist_kernel(const int* __restrict__ dst, int* __restrict__ cnt) {
    int i = blockIdx.x * blockDim.x + threadIdx.x;
    if (i < NE) atomicAdd(&cnt[dst[i]], 1);
}

__global__ void dinv_kernel(const int* __restrict__ cnt, float* __restrict__ dinv) {
    int i = blockIdx.x * blockDim.x + threadIdx.x;
    if (i < NN) dinv[i] = rsqrtf((float)cnt[i] + 1.0f);
}

__global__ void scan1_kernel(const int* __restrict__ cnt, int* __restrict__ bsum) {
    __shared__ int s[256];
    int tid = threadIdx.x;
    int i = blockIdx.x * 256 + tid;
    s[tid] = (i < NN) ? cnt[i] : 0;
    __syncthreads();
    for (int off = 128; off > 0; off >>= 1) {
        if (tid < off) s[tid] += s[tid + off];
        __syncthreads();
    }
    if (tid == 0) bsum[blockIdx.x] = s[0];
}

__global__ void scan2_kernel(int* __restrict__ bsum) {
    if (threadIdx.x == 0 && blockIdx.x == 0) {
        int acc = 0;
        for (int b = 0; b < NB; b++) { int v = bsum[b]; bsum[b] = acc; acc += v; }
        bsum[NB] = acc;
    }
}

__global__ void scan3_kernel(const int* __restrict__ cnt, const int* __restrict__ bsum,
                             int* __restrict__ rowptr) {
    __shared__ int s[256];
    int tid = threadIdx.x;
    int i = blockIdx.x * 256 + tid;
    int v = (i < NN) ? cnt[i] : 0;
    s[tid] = v;
    __syncthreads();
    for (int off = 1; off < 256; off <<= 1) {
        int t = (tid >= off) ? s[tid - off] : 0;
        __syncthreads();
        s[tid] += t;
        __syncthreads();
    }
    if (i < NN) rowptr[i] = bsum[blockIdx.x] + s[tid] - v;
    if (i == NN - 1) rowptr[NN] = bsum[blockIdx.x] + s[tid];
}

// packed edge record: .x = src node, .y = bitcast(norm weight)
__global__ void fill_kernel(const int* __restrict__ src, const int* __restrict__ dst,
                            const float* __restrict__ dinv, const int* __restrict__ rowptr,
                            int* __restrict__ cur, int2* __restrict__ epk) {
    int i = blockIdx.x * blockDim.x + threadIdx.x;
    if (i >= NE) return;
    int s = src[i], d = dst[i];
    int pos = atomicAdd(&cur[d], 1);
    int idx = rowptr[d] + pos;
    float w = dinv[s] * dinv[d];
    epk[idx] = make_int2(s, __float_as_int(w));
}

// ---------------- weight prep (transposes) ----------------

__global__ void prep_weights(const float* __restrict__ lw, const float* __restrict__ gw,
                             const float* __restrict__ wih, const float* __restrict__ whh,
                             float* __restrict__ lin_wt, float* __restrict__ gcn_wt,
                             float* __restrict__ wih_t, float* __restrict__ whh_t) {
    int i = blockIdx.x * blockDim.x + threadIdx.x;
    if (i < 8192) {              // lin_wt[k*64+j] = lw[j*128+k], k<128, j<64
        int k = i >> 6, j = i & 63;
        lin_wt[k * 64 + j] = lw[j * 128 + k];
    }
    if (i < 122880) {            // gcn_wt[l][k][j] = gw[l][j][k]  (s @ W^T form)
        int l = i >> 12, r = i & 4095;
        int k = r >> 6, j = r & 63;
        gcn_wt[l * 4096 + k * 64 + j] = gw[l * 4096 + j * 64 + k];
    }
    if (i < 12288) {             // i = j*64+k, j<192, k<64
        int j = i >> 6, k = i & 63;
        wih_t[k * 192 + j] = wih[i];
        whh_t[k * 192 + j] = whh[i];
    }
}

// ---------------- combined GGC weights ----------------
// WB[l][g][k][j], g<3: Wc_l[k][g*64+j] = sum_m ggw_l[k][m] * wih_t[m][g*64+j]
//                g>=3: whh_t[k][(g-3)*64+j]
// BB[0..191] = bih, BB[192..383] = bhh

__global__ void prep_comb(const float* __restrict__ ggw, const float* __restrict__ wih_t,
                          const float* __restrict__ whh_t, const float* __restrict__ bih,
                          const float* __restrict__ bhh,
                          float* __restrict__ WB, float* __restrict__ BB) {
    int tid = blockIdx.x * blockDim.x + threadIdx.x;
    int wv = tid >> 6, lane = tid & 63;
    if (wv < 24) {               // wv = l*3 + c
        int l = wv / 3, c = wv - l * 3;
        float u[64];
#pragma unroll
        for (int m = 0; m < 64; m++) u[m] = wih_t[m * 192 + c * 64 + lane];
        for (int k = 0; k < 64; k++) {
            float v = ggw[l * 4096 + k * 64 + lane];
            float a0 = 0.f, a1 = 0.f, a2 = 0.f, a3 = 0.f;
#pragma unroll
            for (int m = 0; m < 64; m += 4) {
                a0 = fmaf(lane_bcast(v, m), u[m], a0);
                a1 = fmaf(lane_bcast(v, m + 1), u[m + 1], a1);
                a2 = fmaf(lane_bcast(v, m + 2), u[m + 2], a2);
                a3 = fmaf(lane_bcast(v, m + 3), u[m + 3], a3);
            }
            WB[l * 24576 + c * 4096 + k * 64 + lane] = (a0 + a1) + (a2 + a3);
        }
    }
    int nthr = blockDim.x * gridDim.x;
    for (int idx = tid; idx < 98304; idx += nthr) {
        int l = idx / 12288;
        int rem = idx - l * 12288;
        int c = rem >> 12;
        int r2 = rem & 4095;
        int k = r2 >> 6, j = r2 & 63;
        WB[l * 24576 + (3 + c) * 4096 + k * 64 + j] = whh_t[k * 192 + c * 64 + j];
    }
    if (tid < 384) BB[tid] = (tid < 192) ? bih[tid] : bhh[tid - 192];
}

// ---------------- init linear: h = relu(x @ lw^T + lb), K=128 ----------------

__global__ __launch_bounds__(256, 3) void init_linear(const float* __restrict__ x,
                                                      const float* __restrict__ lin_wt,
                                                      const float* __restrict__ lb,
                                                      float* __restrict__ h) {
    int lane = threadIdx.x & 63;
    int wv = blockIdx.x * (blockDim.x >> 6) + (threadIdx.x >> 6);
    int nw = gridDim.x * (blockDim.x >> 6);
    float w[128];
#pragma unroll
    for (int k = 0; k < 128; k++) w[k] = lin_wt[k * 64 + lane];
#pragma unroll
    for (int k = 0; k < 128; k++) KEEP_VGPR(w[k]);
    float b = lb[lane];
    for (int n = wv; n < NN; n += nw) {
        float x0 = x[n * 128 + lane];
        float x1 = x[n * 128 + 64 + lane];
        float a0 = b, a1 = 0.f, a2 = 0.f, a3 = 0.f;
#pragma unroll
        for (int k = 0; k < 64; k += 4) {
            a0 = fmaf(lane_bcast(x0, k), w[k], a0);
            a1 = fmaf(lane_bcast(x0, k + 1), w[k + 1], a1);
            a2 = fmaf(lane_bcast(x0, k + 2), w[k + 2], a2);
            a3 = fmaf(lane_bcast(x0, k + 3), w[k + 3], a3);
        }
#pragma unroll
        for (int k = 0; k < 64; k += 4) {
            a0 = fmaf(lane_bcast(x1, k), w[64 + k], a0);
            a1 = fmaf(lane_bcast(x1, k + 1), w[64 + k + 1], a1);
            a2 = fmaf(lane_bcast(x1, k + 2), w[64 + k + 2], a2);
            a3 = fmaf(lane_bcast(x1, k + 3), w[64 + k + 3], a3);
        }
        h[n * 64 + lane] = fmaxf((a0 + a1) + (a2 + a3), 0.0f);
    }
}

// ---------------- raw aggregation (tiny VGPR, high occupancy) ----------------
// out[n] = sum_edges w_e * hin[src]  (+ dinv[n]^2 * hin[n] if NORM)

template <bool NORM>
__global__ __launch_bounds__(256) void agg_raw(const float* __restrict__ hin,
                                               const int* __restrict__ rowptr,
                                               const int2* __restrict__ epk,
                                               const float* __restrict__ dinv,
                                               float* __restrict__ out) {
    int lane = threadIdx.x & 63;
    int sub = lane >> 4;
    int q = lane & 15;
    int wv = blockIdx.x * (blockDim.x >> 6) + (threadIdx.x >> 6);
    int nw = gridDim.x * (blockDim.x >> 6);

    for (int n = wv; n < NN; n += nw) {
        int e0 = rowptr[n], e1 = rowptr[n + 1];
        float ax = 0.f, ay = 0.f, az = 0.f, aw = 0.f;

        int e = e0 + sub;
        while (e + 4 < e1) {
            int2 p0 = epk[e];
            int2 p1 = epk[e + 4];
            float4 v0 = *(const float4*)&hin[(size_t)p0.x * 64 + q * 4];
            float4 v1 = *(const float4*)&hin[(size_t)p1.x * 64 + q * 4];
            float w0 = NORM ? __int_as_float(p0.y) : 1.0f;
            float w1 = NORM ? __int_as_float(p1.y) : 1.0f;
            ax = fmaf(w0, v0.x, ax); ay = fmaf(w0, v0.y, ay);
            az = fmaf(w0, v0.z, az); aw = fmaf(w0, v0.w, aw);
            ax = fmaf(w1, v1.x, ax); ay = fmaf(w1, v1.y, ay);
            az = fmaf(w1, v1.z, az); aw = fmaf(w1, v1.w, aw);
            e += 8;
        }
        if (e < e1) {
            int2 p0 = epk[e];
            float4 v0 = *(const float4*)&hin[(size_t)p0.x * 64 + q * 4];
            float w0 = NORM ? __int_as_float(p0.y) : 1.0f;
            ax = fmaf(w0, v0.x, ax); ay = fmaf(w0, v0.y, ay);
            az = fmaf(w0, v0.z, az); aw = fmaf(w0, v0.w, aw);
        }

        ax += __shfl_xor(ax, 16); ay += __shfl_xor(ay, 16);
        az += __shfl_xor(az, 16); aw += __shfl_xor(aw, 16);
        ax += __shfl_xor(ax, 32); ay += __shfl_xor(ay, 32);
        az += __shfl_xor(az, 32); aw += __shfl_xor(aw, 32);

        if (sub == 0) {
            float4 r;
            if (NORM) {
                float di = dinv[n];
                float dd = di * di;
                float4 sv = *(const float4*)&hin[(size_t)n * 64 + q * 4];
                r.x = fmaf(dd, sv.x, ax);
                r.y = fmaf(dd, sv.y, ay);
                r.z = fmaf(dd, sv.z, az);
                r.w = fmaf(dd, sv.w, aw);
            } else {
                r.x = ax; r.y = ay; r.z = az; r.w = aw;
            }
            *(float4*)&out[(size_t)n * 64 + q * 4] = r;
        }
    }
}

// ---------------- mm64b: out[n][j] = bias[j] + sum_k in[n][k] * wt[k][j] -----

__global__ __launch_bounds__(256, 4) void mm64b(const float* __restrict__ in,
                                                const float* __restrict__ wt,
                                                const float* __restrict__ bias,
                                                float* __restrict__ out) {
    int lane = threadIdx.x & 63;
    int wv = blockIdx.x * (blockDim.x >> 6) + (threadIdx.x >> 6);
    int nw = gridDim.x * (blockDim.x >> 6);
    float w[64];
#pragma unroll
    for (int k = 0; k < 64; k++) w[k] = wt[k * 64 + lane];
#pragma unroll
    for (int k = 0; k < 64; k++) KEEP_VGPR(w[k]);
    float b = bias[lane];
    for (int n = wv; n < NN; n += nw) {
        float hreg = in[(size_t)n * 64 + lane];
        float a0 = b, a1 = 0.f, a2 = 0.f, a3 = 0.f;
#pragma unroll
        for (int k = 0; k < 64; k += 4) {
            a0 = fmaf(lane_bcast(hreg, k), w[k], a0);
            a1 = fmaf(lane_bcast(hreg, k + 1), w[k + 1], a1);
            a2 = fmaf(lane_bcast(hreg, k + 2), w[k + 2], a2);
            a3 = fmaf(lane_bcast(hreg, k + 3), w[k + 3], a3);
        }
        out[(size_t)n * 64 + lane] = (a0 + a1) + (a2 + a3);
    }
}

// ---------------- fused GGC step: gates (LDS) + GRU blend ----------------
// block = 384 threads = 6 waves; wave g<3: gi chunk g from t1 (combined Wc);
// g>=3: gh chunk g-3 from h. Gates staged in LDS; then blend 6 nodes.

__global__ __launch_bounds__(384, 4) void gru_fused(const float* __restrict__ t1,
                                                    const float* __restrict__ h,
                                                    const float* __restrict__ WBl,
                                                    const float* __restrict__ BB,
                                                    float* __restrict__ hout) {
    __shared__ float lds[NPB * 384];
    int tid = threadIdx.x;
    int g = tid >> 6, lane = tid & 63;
    const float* wptr = WBl + (g << 12);
    float w[64];
#pragma unroll
    for (int k = 0; k < 64; k++) w[k] = wptr[k * 64 + lane];
#pragma unroll
    for (int k = 0; k < 64; k++) KEEP_VGPR(w[k]);
    float bb = BB[g * 64 + lane];
    const float* in = (g < 3) ? t1 : h;

    for (int base = blockIdx.x * NPB; base < NN; base += gridDim.x * NPB) {
        for (int i = 0; i < NPB; i++) {
            int n = base + i;
            if (n < NN) {
                float v = in[(size_t)n * 64 + lane];
                float a0 = bb, a1 = 0.f, a2 = 0.f, a3 = 0.f;
#pragma unroll
                for (int k = 0; k < 64; k += 4) {
                    a0 = fmaf(lane_bcast(v, k), w[k], a0);
                    a1 = fmaf(lane_bcast(v, k + 1), w[k + 1], a1);
                    a2 = fmaf(lane_bcast(v, k + 2), w[k + 2], a2);
                    a3 = fmaf(lane_bcast(v, k + 3), w[k + 3], a3);
                }
                lds[i * 384 + g * 64 + lane] = (a0 + a1) + (a2 + a3);
            }
        }
        __syncthreads();
        int n2 = base + g;
        if (n2 < NN) {
            float ir = lds[g * 384 + lane];
            float iz = lds[g * 384 + 64 + lane];
            float inn = lds[g * 384 + 128 + lane];
            float hr = lds[g * 384 + 192 + lane];
            float hz = lds[g * 384 + 256 + lane];
            float hn = lds[g * 384 + 320 + lane];
            float hv = h[(size_t)n2 * 64 + lane];
            float r = 1.0f / (1.0f + __expf(-(ir + hr)));
            float z = 1.0f / (1.0f + __expf(-(iz + hz)));
            float targ = inn + r * hn;
            float t2 = __expf(2.0f * targ);
            float nn2 = 1.0f - 2.0f / (t2 + 1.0f);
            hout[(size_t)n2 * 64 + lane] = (1.0f - z) * nn2 + z * hv;
        }
        __syncthreads();
    }
}

// ---------------- launch ----------------

extern "C" void kernel_launch(void* const* d_in, const int* in_sizes, int n_in,
                              void* d_out, int out_size, void* d_ws, size_t ws_size,
                              hipStream_t stream) {
    const float* x   = (const float*)d_in[0];
    const int*   ei  = (const int*)d_in[1];
    const int*   src = ei;
    const int*   dst = ei + NE;
    const float* lw  = (const float*)d_in[2];
    const float* lb  = (const float*)d_in[3];
    const float* gw  = (const float*)d_in[4];
    const float* gb  = (const float*)d_in[5];
    const float* ggw = (const float*)d_in[6];
    const float* wih = (const float*)d_in[7];
    const float* whh = (const float*)d_in[8];
    const float* bih = (const float*)d_in[9];
    const float* bhh = (const float*)d_in[10];
    float* outp = (float*)d_out;

    char* ws = (char*)d_ws;
    size_t off = 0;
    auto take = [&](size_t bytes) -> char* {
        char* p = ws + off;
        off += (bytes + 255) & ~(size_t)255;
        return p;
    };
    int*   cnt    = (int*)take(NN * 4);
    int*   cur    = (int*)take(NN * 4);
    int*   rowptr = (int*)take((NN + 1) * 4);
    int*   bsum   = (int*)take((NB + 1) * 4);
    float* dinv   = (float*)take(NN * 4);
    int2*  epk    = (int2*)take((size_t)NE * 8);
    float* lin_wt = (float*)take(8192 * 4);
    float* gcn_wt = (float*)take(122880 * 4);
    float* wih_t  = (float*)take(12288 * 4);
    float* whh_t  = (float*)take(12288 * 4);
    float* WB     = (float*)take(196608 * 4);
    float* BB     = (float*)take(384 * 4);
    float* h      = (float*)take((size_t)NN * 64 * 4);
    float* t1     = (float*)take((size_t)NN * 64 * 4);
    (void)ws_size; (void)in_sizes; (void)n_in; (void)out_size;

    hipMemsetAsync(cnt, 0, NN * 4, stream);
    hipMemsetAsync(cur, 0, NN * 4, stream);

    hist_kernel<<<(NE + 255) / 256, 256, 0, stream>>>(dst, cnt);
    dinv_kernel<<<(NN + 255) / 256, 256, 0, stream>>>(cnt, dinv);
    scan1_kernel<<<NB, 256, 0, stream>>>(cnt, bsum);
    scan2_kernel<<<1, 64, 0, stream>>>(bsum);
    scan3_kernel<<<NB, 256, 0, stream>>>(cnt, bsum, rowptr);
    fill_kernel<<<(NE + 255) / 256, 256, 0, stream>>>(src, dst, dinv, rowptr, cur, epk);
    prep_weights<<<480, 256, 0, stream>>>(lw, gw, wih, whh, lin_wt, gcn_wt, wih_t, whh_t);
    prep_comb<<<96, 256, 0, stream>>>(ggw, wih_t, whh_t, bih, bhh, WB, BB);

    init_linear<<<512, 256, 0, stream>>>(x, lin_wt, lb, h);

    // GCN: t1 = A_norm @ h (raw, incl self-loop); h = t1 @ W^T + b
    for (int l = 0; l < N_GCN; l++) {
        agg_raw<true><<<12500, 256, 0, stream>>>(h, rowptr, epk, dinv, t1);
        mm64b<<<1024, 256, 0, stream>>>(t1, gcn_wt + l * 4096, gb + l * 64, h);
    }

    // GGC: t1 = A @ h (raw); gates+GRU fused (gi uses combined Wc_l)
    for (int l = 0; l < N_GGC; l++) {
        agg_raw<false><<<12500, 256, 0, stream>>>(h, rowptr, epk, nullptr, t1);
        float* hdst = (l == N_GGC - 1) ? outp : h;
        gru_fused<<<1024, 384, 0, stream>>>(t1, h, WB + l * 24576, BB, hdst);
    }
}

// Round 7
// 2592.428 us; speedup vs baseline: 1.0036x; 1.0036x over previous
//
#include <hip/hip_runtime.h>
#include <math.h>

#define NN 50000
#define NE 800000
#define DD 64
#define N_GCN 30
#define N_GGC 8
#define NB ((NN + 255) / 256)
#define NPB 6   // nodes per block-iteration in gru_fused

__device__ __forceinline__ float lane_bcast(float v, int k) {
    return __int_as_float(__builtin_amdgcn_readlane(__float_as_int(v), k));
}

// 64 named scalar weights: SSA values, cannot be demoted to scratch (the
// float w[64] array was never SROA-promoted -> every use was a cache reload;
// VGPR=44 in R5/R6 proved it).
#define L64(M) M(0) M(1) M(2) M(3) M(4) M(5) M(6) M(7) M(8) M(9) \
 M(10) M(11) M(12) M(13) M(14) M(15) M(16) M(17) M(18) M(19) \
 M(20) M(21) M(22) M(23) M(24) M(25) M(26) M(27) M(28) M(29) \
 M(30) M(31) M(32) M(33) M(34) M(35) M(36) M(37) M(38) M(39) \
 M(40) M(41) M(42) M(43) M(44) M(45) M(46) M(47) M(48) M(49) \
 M(50) M(51) M(52) M(53) M(54) M(55) M(56) M(57) M(58) M(59) \
 M(60) M(61) M(62) M(63)

#define L16Q(M) M(0,1,2,3) M(4,5,6,7) M(8,9,10,11) M(12,13,14,15) \
 M(16,17,18,19) M(20,21,22,23) M(24,25,26,27) M(28,29,30,31) \
 M(32,33,34,35) M(36,37,38,39) M(40,41,42,43) M(44,45,46,47) \
 M(48,49,50,51) M(52,53,54,55) M(56,57,58,59) M(60,61,62,63)

#define DW(k) float w##k = Wp[(k) * 64 + lane];
#define FQ(k0,k1,k2,k3) \
    a0 = fmaf(lane_bcast(hreg, k0), w##k0, a0); \
    a1 = fmaf(lane_bcast(hreg, k1), w##k1, a1); \
    a2 = fmaf(lane_bcast(hreg, k2), w##k2, a2); \
    a3 = fmaf(lane_bcast(hreg, k3), w##k3, a3);

// ---------------- graph prep ----------------

__global__ void hist_kernel(const int* __restrict__ dst, int* __restrict__ cnt) {
    int i = blockIdx.x * blockDim.x + threadIdx.x;
    if (i < NE) atomicAdd(&cnt[dst[i]], 1);
}

__global__ void dinv_kernel(const int* __restrict__ cnt, float* __restrict__ dinv) {
    int i = blockIdx.x * blockDim.x + threadIdx.x;
    if (i < NN) dinv[i] = rsqrtf((float)cnt[i] + 1.0f);
}

__global__ void scan1_kernel(const int* __restrict__ cnt, int* __restrict__ bsum) {
    __shared__ int s[256];
    int tid = threadIdx.x;
    int i = blockIdx.x * 256 + tid;
    s[tid] = (i < NN) ? cnt[i] : 0;
    __syncthreads();
    for (int off = 128; off > 0; off >>= 1) {
        if (tid < off) s[tid] += s[tid + off];
        __syncthreads();
    }
    if (tid == 0) bsum[blockIdx.x] = s[0];
}

__global__ void scan2_kernel(int* __restrict__ bsum) {
    if (threadIdx.x == 0 && blockIdx.x == 0) {
        int acc = 0;
        for (int b = 0; b < NB; b++) { int v = bsum[b]; bsum[b] = acc; acc += v; }
        bsum[NB] = acc;
    }
}

__global__ void scan3_kernel(const int* __restrict__ cnt, const int* __restrict__ bsum,
                             int* __restrict__ rowptr) {
    __shared__ int s[256];
    int tid = threadIdx.x;
    int i = blockIdx.x * 256 + tid;
    int v = (i < NN) ? cnt[i] : 0;
    s[tid] = v;
    __syncthreads();
    for (int off = 1; off < 256; off <<= 1) {
        int t = (tid >= off) ? s[tid - off] : 0;
        __syncthreads();
        s[tid] += t;
        __syncthreads();
    }
    if (i < NN) rowptr[i] = bsum[blockIdx.x] + s[tid] - v;
    if (i == NN - 1) rowptr[NN] = bsum[blockIdx.x] + s[tid];
}

// packed edge record: .x = src node, .y = bitcast(norm weight)
__global__ void fill_kernel(const int* __restrict__ src, const int* __restrict__ dst,
                            const float* __restrict__ dinv, const int* __restrict__ rowptr,
                            int* __restrict__ cur, int2* __restrict__ epk) {
    int i = blockIdx.x * blockDim.x + threadIdx.x;
    if (i >= NE) return;
    int s = src[i], d = dst[i];
    int pos = atomicAdd(&cur[d], 1);
    int idx = rowptr[d] + pos;
    float w = dinv[s] * dinv[d];
    epk[idx] = make_int2(s, __float_as_int(w));
}

// ---------------- weight prep (transposes) ----------------

__global__ void prep_weights(const float* __restrict__ lw, const float* __restrict__ gw,
                             const float* __restrict__ wih, const float* __restrict__ whh,
                             float* __restrict__ lin_wt, float* __restrict__ gcn_wt,
                             float* __restrict__ wih_t, float* __restrict__ whh_t) {
    int i = blockIdx.x * blockDim.x + threadIdx.x;
    if (i < 8192) {              // lin_wt[k*64+j] = lw[j*128+k], k<128, j<64
        int k = i >> 6, j = i & 63;
        lin_wt[k * 64 + j] = lw[j * 128 + k];
    }
    if (i < 122880) {            // gcn_wt[l][k][j] = gw[l][j][k]  (s @ W^T form)
        int l = i >> 12, r = i & 4095;
        int k = r >> 6, j = r & 63;
        gcn_wt[l * 4096 + k * 64 + j] = gw[l * 4096 + j * 64 + k];
    }
    if (i < 12288) {             // i = j*64+k, j<192, k<64
        int j = i >> 6, k = i & 63;
        wih_t[k * 192 + j] = wih[i];
        whh_t[k * 192 + j] = whh[i];
    }
}

// ---------------- combined GGC weights ----------------
// WB[l][g][k][j], g<3: Wc_l[k][g*64+j] = sum_m ggw_l[k][m] * wih_t[m][g*64+j]
//                g>=3: whh_t[k][(g-3)*64+j]
// BB[0..191] = bih, BB[192..383] = bhh

__global__ void prep_comb(const float* __restrict__ ggw, const float* __restrict__ wih_t,
                          const float* __restrict__ whh_t, const float* __restrict__ bih,
                          const float* __restrict__ bhh,
                          float* __restrict__ WB, float* __restrict__ BB) {
    int tid = blockIdx.x * blockDim.x + threadIdx.x;
    int wv = tid >> 6, lane = tid & 63;
    if (wv < 24) {               // wv = l*3 + c
        int l = wv / 3, c = wv - l * 3;
        float u[64];
#pragma unroll
        for (int m = 0; m < 64; m++) u[m] = wih_t[m * 192 + c * 64 + lane];
        for (int k = 0; k < 64; k++) {
            float v = ggw[l * 4096 + k * 64 + lane];
            float a0 = 0.f, a1 = 0.f, a2 = 0.f, a3 = 0.f;
#pragma unroll
            for (int m = 0; m < 64; m += 4) {
                a0 = fmaf(lane_bcast(v, m), u[m], a0);
                a1 = fmaf(lane_bcast(v, m + 1), u[m + 1], a1);
                a2 = fmaf(lane_bcast(v, m + 2), u[m + 2], a2);
                a3 = fmaf(lane_bcast(v, m + 3), u[m + 3], a3);
            }
            WB[l * 24576 + c * 4096 + k * 64 + lane] = (a0 + a1) + (a2 + a3);
        }
    }
    int nthr = blockDim.x * gridDim.x;
    for (int idx = tid; idx < 98304; idx += nthr) {
        int l = idx / 12288;
        int rem = idx - l * 12288;
        int c = rem >> 12;
        int r2 = rem & 4095;
        int k = r2 >> 6, j = r2 & 63;
        WB[l * 24576 + (3 + c) * 4096 + k * 64 + j] = whh_t[k * 192 + c * 64 + j];
    }
    if (tid < 384) BB[tid] = (tid < 192) ? bih[tid] : bhh[tid - 192];
}

// ---------------- init linear: h = relu(x @ lw^T + lb), K=128 ----------------
// Runs once (~10 us) — array version left as-is.

__global__ __launch_bounds__(256) void init_linear(const float* __restrict__ x,
                                                   const float* __restrict__ lin_wt,
                                                   const float* __restrict__ lb,
                                                   float* __restrict__ h) {
    int lane = threadIdx.x & 63;
    int wv = blockIdx.x * (blockDim.x >> 6) + (threadIdx.x >> 6);
    int nw = gridDim.x * (blockDim.x >> 6);
    float w[128];
#pragma unroll
    for (int k = 0; k < 128; k++) w[k] = lin_wt[k * 64 + lane];
    float b = lb[lane];
    for (int n = wv; n < NN; n += nw) {
        float x0 = x[n * 128 + lane];
        float x1 = x[n * 128 + 64 + lane];
        float a0 = b, a1 = 0.f, a2 = 0.f, a3 = 0.f;
#pragma unroll
        for (int k = 0; k < 64; k += 4) {
            a0 = fmaf(lane_bcast(x0, k), w[k], a0);
            a1 = fmaf(lane_bcast(x0, k + 1), w[k + 1], a1);
            a2 = fmaf(lane_bcast(x0, k + 2), w[k + 2], a2);
            a3 = fmaf(lane_bcast(x0, k + 3), w[k + 3], a3);
        }
#pragma unroll
        for (int k = 0; k < 64; k += 4) {
            a0 = fmaf(lane_bcast(x1, k), w[64 + k], a0);
            a1 = fmaf(lane_bcast(x1, k + 1), w[64 + k + 1], a1);
            a2 = fmaf(lane_bcast(x1, k + 2), w[64 + k + 2], a2);
            a3 = fmaf(lane_bcast(x1, k + 3), w[64 + k + 3], a3);
        }
        h[n * 64 + lane] = fmaxf((a0 + a1) + (a2 + a3), 0.0f);
    }
}

// ---------------- raw aggregation (tiny VGPR, high occupancy) ----------------
// out[n] = sum_edges w_e * hin[src]  (+ dinv[n]^2 * hin[n] if NORM)

template <bool NORM>
__global__ __launch_bounds__(256) void agg_raw(const float* __restrict__ hin,
                                               const int* __restrict__ rowptr,
                                               const int2* __restrict__ epk,
                                               const float* __restrict__ dinv,
                                               float* __restrict__ out) {
    int lane = threadIdx.x & 63;
    int sub = lane >> 4;
    int q = lane & 15;
    int wv = blockIdx.x * (blockDim.x >> 6) + (threadIdx.x >> 6);
    int nw = gridDim.x * (blockDim.x >> 6);

    for (int n = wv; n < NN; n += nw) {
        int e0 = rowptr[n], e1 = rowptr[n + 1];
        float ax = 0.f, ay = 0.f, az = 0.f, aw = 0.f;

        int e = e0 + sub;
        while (e + 4 < e1) {
            int2 p0 = epk[e];
            int2 p1 = epk[e + 4];
            float4 v0 = *(const float4*)&hin[(size_t)p0.x * 64 + q * 4];
            float4 v1 = *(const float4*)&hin[(size_t)p1.x * 64 + q * 4];
            float w0 = NORM ? __int_as_float(p0.y) : 1.0f;
            float w1 = NORM ? __int_as_float(p1.y) : 1.0f;
            ax = fmaf(w0, v0.x, ax); ay = fmaf(w0, v0.y, ay);
            az = fmaf(w0, v0.z, az); aw = fmaf(w0, v0.w, aw);
            ax = fmaf(w1, v1.x, ax); ay = fmaf(w1, v1.y, ay);
            az = fmaf(w1, v1.z, az); aw = fmaf(w1, v1.w, aw);
            e += 8;
        }
        if (e < e1) {
            int2 p0 = epk[e];
            float4 v0 = *(const float4*)&hin[(size_t)p0.x * 64 + q * 4];
            float w0 = NORM ? __int_as_float(p0.y) : 1.0f;
            ax = fmaf(w0, v0.x, ax); ay = fmaf(w0, v0.y, ay);
            az = fmaf(w0, v0.z, az); aw = fmaf(w0, v0.w, aw);
        }

        ax += __shfl_xor(ax, 16); ay += __shfl_xor(ay, 16);
        az += __shfl_xor(az, 16); aw += __shfl_xor(aw, 16);
        ax += __shfl_xor(ax, 32); ay += __shfl_xor(ay, 32);
        az += __shfl_xor(az, 32); aw += __shfl_xor(aw, 32);

        if (sub == 0) {
            float4 r;
            if (NORM) {
                float di = dinv[n];
                float dd = di * di;
                float4 sv = *(const float4*)&hin[(size_t)n * 64 + q * 4];
                r.x = fmaf(dd, sv.x, ax);
                r.y = fmaf(dd, sv.y, ay);
                r.z = fmaf(dd, sv.z, az);
                r.w = fmaf(dd, sv.w, aw);
            } else {
                r.x = ax; r.y = ay; r.z = az; r.w = aw;
            }
            *(float4*)&out[(size_t)n * 64 + q * 4] = r;
        }
    }
}

// ---------------- mm64b: out[n][j] = bias[j] + sum_k in[n][k] * wt[k][j] -----
// Weights in 64 NAMED scalars -> true VGPR residency.

__global__ __launch_bounds__(256, 4) void mm64b(const float* __restrict__ in,
                                                const float* __restrict__ wt,
                                                const float* __restrict__ bias,
                                                float* __restrict__ out) {
    int lane = threadIdx.x & 63;
    int wv = blockIdx.x * (blockDim.x >> 6) + (threadIdx.x >> 6);
    int nw = gridDim.x * (blockDim.x >> 6);
    const float* __restrict__ Wp = wt;
    L64(DW)
    float b = bias[lane];
    for (int n = wv; n < NN; n += nw) {
        float hreg = in[(size_t)n * 64 + lane];
        float a0 = b, a1 = 0.f, a2 = 0.f, a3 = 0.f;
        L16Q(FQ)
        out[(size_t)n * 64 + lane] = (a0 + a1) + (a2 + a3);
    }
}

// ---------------- fused GGC step: gates (LDS) + GRU blend ----------------
// block = 384 threads = 6 waves; wave g<3: gi chunk g from t1 (combined Wc);
// g>=3: gh chunk g-3 from h. Gates staged in LDS; then blend 6 nodes.

__global__ __launch_bounds__(384, 4) void gru_fused(const float* __restrict__ t1,
                                                    const float* __restrict__ h,
                                                    const float* __restrict__ WBl,
                                                    const float* __restrict__ BB,
                                                    float* __restrict__ hout) {
    __shared__ float lds[NPB * 384];
    int tid = threadIdx.x;
    int g = tid >> 6, lane = tid & 63;
    const float* __restrict__ Wp = WBl + (g << 12);
    L64(DW)
    float bb = BB[g * 64 + lane];
    const float* in = (g < 3) ? t1 : h;

    for (int base = blockIdx.x * NPB; base < NN; base += gridDim.x * NPB) {
        for (int i = 0; i < NPB; i++) {
            int n = base + i;
            if (n < NN) {
                float hreg = in[(size_t)n * 64 + lane];
                float a0 = bb, a1 = 0.f, a2 = 0.f, a3 = 0.f;
                L16Q(FQ)
                lds[i * 384 + g * 64 + lane] = (a0 + a1) + (a2 + a3);
            }
        }
        __syncthreads();
        int n2 = base + g;
        if (n2 < NN) {
            float ir = lds[g * 384 + lane];
            float iz = lds[g * 384 + 64 + lane];
            float inn = lds[g * 384 + 128 + lane];
            float hr = lds[g * 384 + 192 + lane];
            float hz = lds[g * 384 + 256 + lane];
            float hn = lds[g * 384 + 320 + lane];
            float hv = h[(size_t)n2 * 64 + lane];
            float r = 1.0f / (1.0f + __expf(-(ir + hr)));
            float z = 1.0f / (1.0f + __expf(-(iz + hz)));
            float targ = inn + r * hn;
            float t2 = __expf(2.0f * targ);
            float nn2 = 1.0f - 2.0f / (t2 + 1.0f);
            hout[(size_t)n2 * 64 + lane] = (1.0f - z) * nn2 + z * hv;
        }
        __syncthreads();
    }
}

// ---------------- launch ----------------

extern "C" void kernel_launch(void* const* d_in, const int* in_sizes, int n_in,
                              void* d_out, int out_size, void* d_ws, size_t ws_size,
                              hipStream_t stream) {
    const float* x   = (const float*)d_in[0];
    const int*   ei  = (const int*)d_in[1];
    const int*   src = ei;
    const int*   dst = ei + NE;
    const float* lw  = (const float*)d_in[2];
    const float* lb  = (const float*)d_in[3];
    const float* gw  = (const float*)d_in[4];
    const float* gb  = (const float*)d_in[5];
    const float* ggw = (const float*)d_in[6];
    const float* wih = (const float*)d_in[7];
    const float* whh = (const float*)d_in[8];
    const float* bih = (const float*)d_in[9];
    const float* bhh = (const float*)d_in[10];
    float* outp = (float*)d_out;

    char* ws = (char*)d_ws;
    size_t off = 0;
    auto take = [&](size_t bytes) -> char* {
        char* p = ws + off;
        off += (bytes + 255) & ~(size_t)255;
        return p;
    };
    int*   cnt    = (int*)take(NN * 4);
    int*   cur    = (int*)take(NN * 4);
    int*   rowptr = (int*)take((NN + 1) * 4);
    int*   bsum   = (int*)take((NB + 1) * 4);
    float* dinv   = (float*)take(NN * 4);
    int2*  epk    = (int2*)take((size_t)NE * 8);
    float* lin_wt = (float*)take(8192 * 4);
    float* gcn_wt = (float*)take(122880 * 4);
    float* wih_t  = (float*)take(12288 * 4);
    float* whh_t  = (float*)take(12288 * 4);
    float* WB     = (float*)take(196608 * 4);
    float* BB     = (float*)take(384 * 4);
    float* h      = (float*)take((size_t)NN * 64 * 4);
    float* t1     = (float*)take((size_t)NN * 64 * 4);
    (void)ws_size; (void)in_sizes; (void)n_in; (void)out_size;

    hipMemsetAsync(cnt, 0, NN * 4, stream);
    hipMemsetAsync(cur, 0, NN * 4, stream);

    hist_kernel<<<(NE + 255) / 256, 256, 0, stream>>>(dst, cnt);
    dinv_kernel<<<(NN + 255) / 256, 256, 0, stream>>>(cnt, dinv);
    scan1_kernel<<<NB, 256, 0, stream>>>(cnt, bsum);
    scan2_kernel<<<1, 64, 0, stream>>>(bsum);
    scan3_kernel<<<NB, 256, 0, stream>>>(cnt, bsum, rowptr);
    fill_kernel<<<(NE + 255) / 256, 256, 0, stream>>>(src, dst, dinv, rowptr, cur, epk);
    prep_weights<<<480, 256, 0, stream>>>(lw, gw, wih, whh, lin_wt, gcn_wt, wih_t, whh_t);
    prep_comb<<<96, 256, 0, stream>>>(ggw, wih_t, whh_t, bih, bhh, WB, BB);

    init_linear<<<512, 256, 0, stream>>>(x, lin_wt, lb, h);

    // GCN: t1 = A_norm @ h (raw, incl self-loop); h = t1 @ W^T + b
    for (int l = 0; l < N_GCN; l++) {
        agg_raw<true><<<12500, 256, 0, stream>>>(h, rowptr, epk, dinv, t1);
        mm64b<<<1024, 256, 0, stream>>>(t1, gcn_wt + l * 4096, gb + l * 64, h);
    }

    // GGC: t1 = A @ h (raw); gates+GRU fused (gi uses combined Wc_l)
    for (int l = 0; l < N_GGC; l++) {
        agg_raw<false><<<12500, 256, 0, stream>>>(h, rowptr, epk, nullptr, t1);
        float* hdst = (l == N_GGC - 1) ? outp : h;
        gru_fused<<<1024, 384, 0, stream>>>(t1, h, WB + l * 24576, BB, hdst);
    }
}